// Round 1
// baseline (10737.506 us; speedup 1.0000x reference)
//
#include <hip/hip_runtime.h>

#define VIEWS 360
#define NDET 736
#define NX 512
#define NY 512
#define NPIX (NX * NY)

// ---------------------------------------------------------------------------
// Linear layer: out[v,d] = relu(b[d] + sum_k in[v,k] * w[d,k])
// One block per v (360 blocks). x-row staged in LDS, w rows streamed float4.
// ---------------------------------------------------------------------------
__global__ __launch_bounds__(256) void linear_relu_kernel(
    const float* __restrict__ in, const float* __restrict__ w,
    const float* __restrict__ b, float* __restrict__ out) {
  __shared__ __align__(16) float xin[NDET];
  const int v = blockIdx.x;
  const float4* src4 = (const float4*)(in + v * NDET);
  float4* dst4 = (float4*)xin;
  for (int k = threadIdx.x; k < NDET / 4; k += 256) dst4[k] = src4[k];
  __syncthreads();

  for (int d = threadIdx.x; d < NDET; d += 256) {
    const float4* w4 = (const float4*)(w + d * NDET);
    float acc = 0.f;
#pragma unroll 8
    for (int k = 0; k < NDET / 4; ++k) {
      float4 xv = ((const float4*)xin)[k];
      float4 wv = w4[k];
      acc = fmaf(xv.x, wv.x, acc);
      acc = fmaf(xv.y, wv.y, acc);
      acc = fmaf(xv.z, wv.z, acc);
      acc = fmaf(xv.w, wv.w, acc);
    }
    out[v * NDET + d] = fmaxf(acc + b[d], 0.f);
  }
}

// ---------------------------------------------------------------------------
// Backprojection: img_flipped[p'] = scale * sum_a sino[idx[p*360+a]]
// One thread per pixel. idx loaded as int4 (360 = 90*4, 1440B/thread aligned).
// Writes directly in flipped orientation.
// ---------------------------------------------------------------------------
__global__ __launch_bounds__(256) void backproj_kernel(
    const float* __restrict__ sino, const int* __restrict__ idx,
    float* __restrict__ img) {
  const int p = blockIdx.x * 256 + threadIdx.x;
  const int4* ip4 = (const int4*)(idx + (size_t)p * VIEWS);
  float acc = 0.f;
#pragma unroll 5
  for (int a = 0; a < VIEWS / 4; ++a) {
    int4 v = ip4[a];
    acc += sino[v.x];
    acc += sino[v.y];
    acc += sino[v.z];
    acc += sino[v.w];
  }
  const int ix = p >> 9, iy = p & 511;
  const int q = (NX - 1 - ix) * NY + (NY - 1 - iy);
  img[q] = acc * 0.00872665f;  // END_ANGLE / (2*VIEWS)
}

// ---------------------------------------------------------------------------
// 3x3 SAME-pad neighborhood load (zero pad), one channel plane.
// ---------------------------------------------------------------------------
__device__ __forceinline__ void load9(const float* __restrict__ base, int gx,
                                      int gy, float v[9]) {
  const bool xm = gx > 0, xp = gx < NX - 1, ym = gy > 0, yp = gy < NY - 1;
  const float* c = base + gy * NX + gx;
  v[0] = (ym && xm) ? c[-NX - 1] : 0.f;
  v[1] = (ym)       ? c[-NX]     : 0.f;
  v[2] = (ym && xp) ? c[-NX + 1] : 0.f;
  v[3] = (xm)       ? c[-1]      : 0.f;
  v[4] =               c[0];
  v[5] = (xp)       ? c[1]       : 0.f;
  v[6] = (yp && xm) ? c[NX - 1]  : 0.f;
  v[7] = (yp)       ? c[NX]      : 0.f;
  v[8] = (yp && xp) ? c[NX + 1]  : 0.f;
}

__device__ __forceinline__ float dot9(float a, const float v[9],
                                      const float* __restrict__ w) {
  a = fmaf(v[0], w[0], a);
  a = fmaf(v[1], w[1], a);
  a = fmaf(v[2], w[2], a);
  a = fmaf(v[3], w[3], a);
  a = fmaf(v[4], w[4], a);
  a = fmaf(v[5], w[5], a);
  a = fmaf(v[6], w[6], a);
  a = fmaf(v[7], w[7], a);
  a = fmaf(v[8], w[8], a);
  return a;
}

// ---------------------------------------------------------------------------
// conv_in: 1 -> 64 channels, 3x3 SAME, ReLU. One thread per pixel.
// ---------------------------------------------------------------------------
__global__ __launch_bounds__(256) void conv_in_kernel(
    const float* __restrict__ in, const float* __restrict__ w,
    const float* __restrict__ b, float* __restrict__ out) {
  const int p = blockIdx.x * 256 + threadIdx.x;
  const int gx = p & (NX - 1), gy = p >> 9;
  float v[9];
  load9(in, gx, gy, v);
#pragma unroll
  for (int oc = 0; oc < 64; ++oc) {
    float a = dot9(b[oc], v, w + oc * 9);
    out[oc * NPIX + p] = fmaxf(a, 0.f);
  }
}

// ---------------------------------------------------------------------------
// conv64: 64 -> 64 channels, 3x3 SAME. Thread = 1 pixel, 64 output channels.
// Weight index is wave-uniform -> scalar loads. acc[] fully unrolled (VGPRs).
// Block tile: 64 wide x 4 tall.
// ---------------------------------------------------------------------------
template <int RELU, int ADDRES>
__global__ __launch_bounds__(256) void conv64_kernel(
    const float* __restrict__ in, const float* __restrict__ w,
    const float* __restrict__ b, const float* __restrict__ res,
    float* __restrict__ out) {
  const int tx = threadIdx.x & 63, ty = threadIdx.x >> 6;
  const int gx = (blockIdx.x & 7) * 64 + tx;
  const int gy = (blockIdx.x >> 3) * 4 + ty;

  float acc[64];
#pragma unroll
  for (int o = 0; o < 64; ++o) acc[o] = 0.f;

  for (int ic = 0; ic < 64; ++ic) {
    float v[9];
    load9(in + ic * NPIX, gx, gy, v);
    const float* wic = w + ic * 9;  // w[(oc*64 + ic)*9 + j] = wic[oc*576 + j]
#pragma unroll
    for (int oc = 0; oc < 64; ++oc) {
      acc[oc] = dot9(acc[oc], v, wic + oc * 576);
    }
  }

  const int p = gy * NX + gx;
#pragma unroll
  for (int oc = 0; oc < 64; ++oc) {
    float val = acc[oc] + b[oc];
    if (ADDRES) val += res[oc * NPIX + p];
    if (RELU) val = fmaxf(val, 0.f);
    out[oc * NPIX + p] = val;
  }
}

// ---------------------------------------------------------------------------
// conv_out: 64 -> 1 channel, 3x3 SAME, no ReLU. One thread per pixel.
// ---------------------------------------------------------------------------
__global__ __launch_bounds__(256) void conv_out_kernel(
    const float* __restrict__ in, const float* __restrict__ w,
    const float* __restrict__ b, float* __restrict__ out) {
  const int p = blockIdx.x * 256 + threadIdx.x;
  const int gx = p & (NX - 1), gy = p >> 9;
  float a = b[0];
  for (int ic = 0; ic < 64; ++ic) {
    float v[9];
    load9(in + ic * NPIX, gx, gy, v);
    a = dot9(a, v, w + ic * 9);
  }
  out[p] = a;
}

// ---------------------------------------------------------------------------
extern "C" void kernel_launch(void* const* d_in, const int* in_sizes, int n_in,
                              void* d_out, int out_size, void* d_ws,
                              size_t ws_size, hipStream_t stream) {
  const float* x      = (const float*)d_in[0];
  const int*   indices= (const int*)d_in[1];   // int64 -> int32 under JAX x64-off
  const float* w1     = (const float*)d_in[2];
  const float* b1     = (const float*)d_in[3];
  const float* w2     = (const float*)d_in[4];
  const float* b2     = (const float*)d_in[5];
  const float* cin_w  = (const float*)d_in[6];
  const float* cin_b  = (const float*)d_in[7];
  const float* bw1    = (const float*)d_in[8];
  const float* bb1    = (const float*)d_in[9];
  const float* bw2    = (const float*)d_in[10];
  const float* bb2    = (const float*)d_in[11];
  const float* cout_w = (const float*)d_in[12];
  const float* cout_b = (const float*)d_in[13];

  float* ws  = (float*)d_ws;
  float* h1  = ws;                    // 360*736   = 264960
  float* h2  = h1 + VIEWS * NDET;     // 264960
  float* img = h2 + VIEWS * NDET;     // 262144
  float* y   = img + NPIX;            // 64*262144 = 16777216
  float* z   = y + 64 * NPIX;         // 16777216
  // total ~137.4 MB of d_ws

  linear_relu_kernel<<<VIEWS, 256, 0, stream>>>(x, w1, b1, h1);
  linear_relu_kernel<<<VIEWS, 256, 0, stream>>>(h1, w2, b2, h2);
  backproj_kernel<<<NPIX / 256, 256, 0, stream>>>(h2, indices, img);
  conv_in_kernel<<<NPIX / 256, 256, 0, stream>>>(img, cin_w, cin_b, y);
  for (int i = 0; i < 11; ++i) {
    conv64_kernel<1, 0><<<NPIX / 256, 256, 0, stream>>>(
        y, bw1 + i * 36864, bb1 + i * 64, nullptr, z);
    conv64_kernel<1, 1><<<NPIX / 256, 256, 0, stream>>>(
        z, bw2 + i * 36864, bb2 + i * 64, y, y);
  }
  conv_out_kernel<<<NPIX / 256, 256, 0, stream>>>(y, cout_w, cout_b,
                                                  (float*)d_out);
}

// Round 2
// 9820.798 us; speedup vs baseline: 1.0933x; 1.0933x over previous
//
#include <hip/hip_runtime.h>

#define VIEWS 360
#define NDET 736
#define NX 512
#define NY 512
#define NPIX (NX * NY)

// ---------------------------------------------------------------------------
// Linear layer: out[v,d] = relu(b[d] + sum_k in[v,k] * w[d,k])
// ---------------------------------------------------------------------------
__global__ __launch_bounds__(256) void linear_relu_kernel(
    const float* __restrict__ in, const float* __restrict__ w,
    const float* __restrict__ b, float* __restrict__ out) {
  __shared__ __align__(16) float xin[NDET];
  const int v = blockIdx.x;
  const float4* src4 = (const float4*)(in + v * NDET);
  float4* dst4 = (float4*)xin;
  for (int k = threadIdx.x; k < NDET / 4; k += 256) dst4[k] = src4[k];
  __syncthreads();

  for (int d = threadIdx.x; d < NDET; d += 256) {
    const float4* w4 = (const float4*)(w + d * NDET);
    float acc = 0.f;
#pragma unroll 8
    for (int k = 0; k < NDET / 4; ++k) {
      float4 xv = ((const float4*)xin)[k];
      float4 wv = w4[k];
      acc = fmaf(xv.x, wv.x, acc);
      acc = fmaf(xv.y, wv.y, acc);
      acc = fmaf(xv.z, wv.z, acc);
      acc = fmaf(xv.w, wv.w, acc);
    }
    out[v * NDET + d] = fmaxf(acc + b[d], 0.f);
  }
}

// ---------------------------------------------------------------------------
// Backprojection: img_flipped[p'] = scale * sum_a sino[idx[p*360+a]]
// ---------------------------------------------------------------------------
__global__ __launch_bounds__(256) void backproj_kernel(
    const float* __restrict__ sino, const int* __restrict__ idx,
    float* __restrict__ img) {
  const int p = blockIdx.x * 256 + threadIdx.x;
  const int4* ip4 = (const int4*)(idx + (size_t)p * VIEWS);
  float acc = 0.f;
#pragma unroll 5
  for (int a = 0; a < VIEWS / 4; ++a) {
    int4 v = ip4[a];
    acc += sino[v.x];
    acc += sino[v.y];
    acc += sino[v.z];
    acc += sino[v.w];
  }
  const int ix = p >> 9, iy = p & 511;
  const int q = (NX - 1 - ix) * NY + (NY - 1 - iy);
  img[q] = acc * 0.00872665f;  // END_ANGLE / (2*VIEWS)
}

// ---------------------------------------------------------------------------
// 3x3 SAME-pad neighborhood load (zero pad), one channel plane.
// ---------------------------------------------------------------------------
__device__ __forceinline__ void load9(const float* __restrict__ base, int gx,
                                      int gy, float v[9]) {
  const bool xm = gx > 0, xp = gx < NX - 1, ym = gy > 0, yp = gy < NY - 1;
  const float* c = base + gy * NX + gx;
  v[0] = (ym && xm) ? c[-NX - 1] : 0.f;
  v[1] = (ym)       ? c[-NX]     : 0.f;
  v[2] = (ym && xp) ? c[-NX + 1] : 0.f;
  v[3] = (xm)       ? c[-1]      : 0.f;
  v[4] =               c[0];
  v[5] = (xp)       ? c[1]       : 0.f;
  v[6] = (yp && xm) ? c[NX - 1]  : 0.f;
  v[7] = (yp)       ? c[NX]      : 0.f;
  v[8] = (yp && xp) ? c[NX + 1]  : 0.f;
}

__device__ __forceinline__ float dot9(float a, const float v[9],
                                      const float* __restrict__ w) {
  a = fmaf(v[0], w[0], a);
  a = fmaf(v[1], w[1], a);
  a = fmaf(v[2], w[2], a);
  a = fmaf(v[3], w[3], a);
  a = fmaf(v[4], w[4], a);
  a = fmaf(v[5], w[5], a);
  a = fmaf(v[6], w[6], a);
  a = fmaf(v[7], w[7], a);
  a = fmaf(v[8], w[8], a);
  return a;
}

// ---------------------------------------------------------------------------
// conv_in: 1 -> 64 channels, 3x3 SAME, ReLU. One thread per pixel.
// ---------------------------------------------------------------------------
__global__ __launch_bounds__(256) void conv_in_kernel(
    const float* __restrict__ in, const float* __restrict__ w,
    const float* __restrict__ b, float* __restrict__ out) {
  const int p = blockIdx.x * 256 + threadIdx.x;
  const int gx = p & (NX - 1), gy = p >> 9;
  float v[9];
  load9(in, gx, gy, v);
#pragma unroll
  for (int oc = 0; oc < 64; ++oc) {
    float a = dot9(b[oc], v, w + oc * 9);
    out[oc * NPIX + p] = fmaxf(a, 0.f);
  }
}

// ---------------------------------------------------------------------------
// conv64: 64 -> 64 channels, 3x3 SAME. Thread = 1 pixel.
// TWO PASSES of 32 output channels each: acc[32] stays in VGPRs (the acc[64]
// version spilled to scratch: VGPR_Count=48, VALUBusy=26%).
// __launch_bounds__(256,2): allow up to 256 VGPRs (min 2 waves/EU).
// ---------------------------------------------------------------------------
template <int RELU, int ADDRES>
__global__ __launch_bounds__(256, 2) void conv64_kernel(
    const float* __restrict__ in, const float* __restrict__ w,
    const float* __restrict__ b, const float* __restrict__ res,
    float* __restrict__ out) {
  const int tx = threadIdx.x & 63, ty = threadIdx.x >> 6;
  const int gx = (blockIdx.x & 7) * 64 + tx;
  const int gy = (blockIdx.x >> 3) * 4 + ty;
  const int p = gy * NX + gx;

#pragma unroll 1
  for (int c = 0; c < 2; ++c) {
    float acc[32];
#pragma unroll
    for (int o = 0; o < 32; ++o) acc[o] = 0.f;

    const float* wc = w + c * 32 * 576;  // w[((c*32+oc)*64 + ic)*9 + j]
#pragma unroll 1
    for (int ic = 0; ic < 64; ++ic) {
      float v[9];
      load9(in + ic * NPIX, gx, gy, v);
      const float* wic = wc + ic * 9;
#pragma unroll
      for (int oc = 0; oc < 32; ++oc) {
        acc[oc] = dot9(acc[oc], v, wic + oc * 576);
      }
    }

#pragma unroll
    for (int oc = 0; oc < 32; ++oc) {
      const int o = c * 32 + oc;
      float val = acc[oc] + b[o];
      if (ADDRES) val += res[o * NPIX + p];
      if (RELU) val = fmaxf(val, 0.f);
      out[o * NPIX + p] = val;
    }
  }
}

// ---------------------------------------------------------------------------
// conv_out: 64 -> 1 channel, 3x3 SAME, no ReLU. One thread per pixel.
// ---------------------------------------------------------------------------
__global__ __launch_bounds__(256) void conv_out_kernel(
    const float* __restrict__ in, const float* __restrict__ w,
    const float* __restrict__ b, float* __restrict__ out) {
  const int p = blockIdx.x * 256 + threadIdx.x;
  const int gx = p & (NX - 1), gy = p >> 9;
  float a = b[0];
  for (int ic = 0; ic < 64; ++ic) {
    float v[9];
    load9(in + ic * NPIX, gx, gy, v);
    a = dot9(a, v, w + ic * 9);
  }
  out[p] = a;
}

// ---------------------------------------------------------------------------
extern "C" void kernel_launch(void* const* d_in, const int* in_sizes, int n_in,
                              void* d_out, int out_size, void* d_ws,
                              size_t ws_size, hipStream_t stream) {
  const float* x      = (const float*)d_in[0];
  const int*   indices= (const int*)d_in[1];
  const float* w1     = (const float*)d_in[2];
  const float* b1     = (const float*)d_in[3];
  const float* w2     = (const float*)d_in[4];
  const float* b2     = (const float*)d_in[5];
  const float* cin_w  = (const float*)d_in[6];
  const float* cin_b  = (const float*)d_in[7];
  const float* bw1    = (const float*)d_in[8];
  const float* bb1    = (const float*)d_in[9];
  const float* bw2    = (const float*)d_in[10];
  const float* bb2    = (const float*)d_in[11];
  const float* cout_w = (const float*)d_in[12];
  const float* cout_b = (const float*)d_in[13];

  float* ws  = (float*)d_ws;
  float* h1  = ws;                    // 360*736
  float* h2  = h1 + VIEWS * NDET;
  float* img = h2 + VIEWS * NDET;
  float* y   = img + NPIX;            // 64*262144
  float* z   = y + 64 * NPIX;

  linear_relu_kernel<<<VIEWS, 256, 0, stream>>>(x, w1, b1, h1);
  linear_relu_kernel<<<VIEWS, 256, 0, stream>>>(h1, w2, b2, h2);
  backproj_kernel<<<NPIX / 256, 256, 0, stream>>>(h2, indices, img);
  conv_in_kernel<<<NPIX / 256, 256, 0, stream>>>(img, cin_w, cin_b, y);
  for (int i = 0; i < 11; ++i) {
    conv64_kernel<1, 0><<<NPIX / 256, 256, 0, stream>>>(
        y, bw1 + i * 36864, bb1 + i * 64, nullptr, z);
    conv64_kernel<1, 1><<<NPIX / 256, 256, 0, stream>>>(
        z, bw2 + i * 36864, bb2 + i * 64, y, y);
  }
  conv_out_kernel<<<NPIX / 256, 256, 0, stream>>>(y, cout_w, cout_b,
                                                  (float*)d_out);
}

// Round 4
// 2495.731 us; speedup vs baseline: 4.3023x; 3.9350x over previous
//
#include <hip/hip_runtime.h>

#define VIEWS 360
#define NDET 736
#define NX 512
#define NY 512
#define NPIX (NX * NY)
#define ICP 68  // padded ic slots: 68*2B=136B x-stride -> 34 dw -> conflict-free

typedef unsigned short u16;
typedef __attribute__((ext_vector_type(4))) short bf16x4;
typedef __attribute__((ext_vector_type(8))) short bf16x8;
typedef __attribute__((ext_vector_type(4))) float f32x4;

__device__ __forceinline__ u16 f2bf(float f) {
  unsigned u = __float_as_uint(f);
  return (u16)((u + 0x7fffu + ((u >> 16) & 1u)) >> 16);
}
__device__ __forceinline__ float bf2f(u16 h) {
  return __uint_as_float(((unsigned)h) << 16);
}

// ---------------------------------------------------------------------------
// Linear layer: out[v,d] = relu(b[d] + sum_k in[v,k] * w[d,k])
// ---------------------------------------------------------------------------
__global__ __launch_bounds__(256) void linear_relu_kernel(
    const float* __restrict__ in, const float* __restrict__ w,
    const float* __restrict__ b, float* __restrict__ out) {
  __shared__ __align__(16) float xin[NDET];
  const int v = blockIdx.x;
  const float4* src4 = (const float4*)(in + v * NDET);
  float4* dst4 = (float4*)xin;
  for (int k = threadIdx.x; k < NDET / 4; k += 256) dst4[k] = src4[k];
  __syncthreads();

  for (int d = threadIdx.x; d < NDET; d += 256) {
    const float4* w4 = (const float4*)(w + d * NDET);
    float acc = 0.f;
#pragma unroll 8
    for (int k = 0; k < NDET / 4; ++k) {
      float4 xv = ((const float4*)xin)[k];
      float4 wv = w4[k];
      acc = fmaf(xv.x, wv.x, acc);
      acc = fmaf(xv.y, wv.y, acc);
      acc = fmaf(xv.z, wv.z, acc);
      acc = fmaf(xv.w, wv.w, acc);
    }
    out[v * NDET + d] = fmaxf(acc + b[d], 0.f);
  }
}

// ---------------------------------------------------------------------------
// Backprojection (fp32 in/out, writes flipped image)
// ---------------------------------------------------------------------------
__global__ __launch_bounds__(256) void backproj_kernel(
    const float* __restrict__ sino, const int* __restrict__ idx,
    float* __restrict__ img) {
  const int p = blockIdx.x * 256 + threadIdx.x;
  const int4* ip4 = (const int4*)(idx + (size_t)p * VIEWS);
  float acc = 0.f;
#pragma unroll 5
  for (int a = 0; a < VIEWS / 4; ++a) {
    int4 v = ip4[a];
    acc += sino[v.x];
    acc += sino[v.y];
    acc += sino[v.z];
    acc += sino[v.w];
  }
  const int ix = p >> 9, iy = p & 511;
  const int q = (NX - 1 - ix) * NY + (NY - 1 - iy);
  img[q] = acc * 0.00872665f;  // END_ANGLE / (2*VIEWS)
}

// ---------------------------------------------------------------------------
// fp32 3x3 neighborhood load (zero pad)
// ---------------------------------------------------------------------------
__device__ __forceinline__ void load9(const float* __restrict__ base, int gx,
                                      int gy, float v[9]) {
  const bool xm = gx > 0, xp = gx < NX - 1, ym = gy > 0, yp = gy < NY - 1;
  const float* c = base + gy * NX + gx;
  v[0] = (ym && xm) ? c[-NX - 1] : 0.f;
  v[1] = (ym)       ? c[-NX]     : 0.f;
  v[2] = (ym && xp) ? c[-NX + 1] : 0.f;
  v[3] = (xm)       ? c[-1]      : 0.f;
  v[4] =               c[0];
  v[5] = (xp)       ? c[1]       : 0.f;
  v[6] = (yp && xm) ? c[NX - 1]  : 0.f;
  v[7] = (yp)       ? c[NX]      : 0.f;
  v[8] = (yp && xp) ? c[NX + 1]  : 0.f;
}

__device__ __forceinline__ float dot9(float a, const float v[9],
                                      const float* __restrict__ w) {
  a = fmaf(v[0], w[0], a);
  a = fmaf(v[1], w[1], a);
  a = fmaf(v[2], w[2], a);
  a = fmaf(v[3], w[3], a);
  a = fmaf(v[4], w[4], a);
  a = fmaf(v[5], w[5], a);
  a = fmaf(v[6], w[6], a);
  a = fmaf(v[7], w[7], a);
  a = fmaf(v[8], w[8], a);
  return a;
}

// ---------------------------------------------------------------------------
// conv_in: 1 -> 64 channels, fp32 in/out (residual stream stays fp32).
// ---------------------------------------------------------------------------
__global__ __launch_bounds__(256) void conv_in_kernel(
    const float* __restrict__ in, const float* __restrict__ w,
    const float* __restrict__ b, float* __restrict__ out) {
  const int p = blockIdx.x * 256 + threadIdx.x;
  const int gx = p & (NX - 1), gy = p >> 9;
  float v[9];
  load9(in, gx, gy, v);
#pragma unroll
  for (int oc = 0; oc < 64; ++oc) {
    float a = dot9(b[oc], v, w + oc * 9);
    out[oc * NPIX + p] = fmaxf(a, 0.f);
  }
}

// ---------------------------------------------------------------------------
// Weight prep: fp32 w[oc][ic][3][3] -> bf16 wAll[layer][oc][k], k = tap*64+ic
// ---------------------------------------------------------------------------
__global__ __launch_bounds__(256) void prep_weights_kernel(
    const float* __restrict__ bw1, const float* __restrict__ bw2,
    u16* __restrict__ wAll) {
  const int g = blockIdx.x * 256 + threadIdx.x;
  if (g >= 22 * 36864) return;
  const int li = g / 36864, rm = g % 36864;
  const int oc = rm / 576, k = rm % 576;
  const int tap = k >> 6, ic = k & 63;
  const float* src = (li < 11) ? bw1 + li * 36864 : bw2 + (li - 11) * 36864;
  wAll[g] = f2bf(src[(oc * 64 + ic) * 9 + tap]);
}

// ---------------------------------------------------------------------------
// conv64 via MFMA implicit GEMM. M=64 oc, N = 64x * 4y px tile, K=576.
// IN_BF: input planes bf16 (else fp32, converted to bf16 during LDS staging).
// OUT_BF: output planes bf16 (else fp32). Residual (res) is always fp32.
// mfma_f32_16x16x32_bf16; C/D col=lane&15, row=(lane>>4)*4+reg (m89-verified).
// ---------------------------------------------------------------------------
template <int IN_BF, int OUT_BF, int RELU, int ADDRES>
__global__ __launch_bounds__(256, 2) void conv64_mfma(
    const void* __restrict__ in_, const u16* __restrict__ wA,
    const float* __restrict__ bias, const float* __restrict__ res,
    void* __restrict__ out_) {
  __shared__ u16 lds[6 * 66 * ICP];
  const int xb = (blockIdx.x & 7) * 64;
  const int yb = (int)(blockIdx.x >> 3) * 4;
  const int tid = threadIdx.x;

  // stage: 6 rows x (x in xb-1..xb+64) x 64 ic -> lds[r][xi][ic], bf16
#pragma unroll 1
  for (int it = 0; it < 27; ++it) {
    const int g = it * 256 + tid;
    const int m4 = g % 18;
    const int ic = (g / 18) & 63;
    const int r = g / (18 * 64);
    const int y = yb - 1 + r;
    const int x0 = xb - 4 + m4 * 4;
    u16 v0 = 0, v1 = 0, v2 = 0, v3 = 0;
    if ((unsigned)y < 512u && (unsigned)x0 <= 508u) {
      if (IN_BF) {
        uint2 d = *(const uint2*)&((const u16*)in_)[ic * NPIX + y * NX + x0];
        v0 = (u16)(d.x & 0xffffu); v1 = (u16)(d.x >> 16);
        v2 = (u16)(d.y & 0xffffu); v3 = (u16)(d.y >> 16);
      } else {
        float4 d = *(const float4*)&((const float*)in_)[ic * NPIX + y * NX + x0];
        v0 = f2bf(d.x); v1 = f2bf(d.y); v2 = f2bf(d.z); v3 = f2bf(d.w);
      }
    }
    const int xi0 = x0 - xb + 1;
    if ((unsigned)(xi0 + 0) < 66u) lds[(r * 66 + xi0 + 0) * ICP + ic] = v0;
    if ((unsigned)(xi0 + 1) < 66u) lds[(r * 66 + xi0 + 1) * ICP + ic] = v1;
    if ((unsigned)(xi0 + 2) < 66u) lds[(r * 66 + xi0 + 2) * ICP + ic] = v2;
    if ((unsigned)(xi0 + 3) < 66u) lds[(r * 66 + xi0 + 3) * ICP + ic] = v3;
  }
  __syncthreads();

  const int wv = tid >> 6;   // y-offset 0..3
  const int lane = tid & 63;
  const int n = lane & 15;
  const int kg = lane >> 4;

  f32x4 acc[4][4];
#pragma unroll
  for (int i = 0; i < 4; ++i)
#pragma unroll
    for (int j = 0; j < 4; ++j) acc[i][j] = (f32x4){0.f, 0.f, 0.f, 0.f};

#pragma unroll 1
  for (int tap = 0; tap < 9; ++tap) {
    const int r = wv + tap / 3;
    const int dx = tap % 3 - 1;
    const u16* lrow = &lds[(r * 66 + dx + 1) * ICP];
#pragma unroll
    for (int kb = 0; kb < 2; ++kb) {
      const int icl = kb * 32 + kg * 8;
      const int k = tap * 64 + icl;
      bf16x8 afr[4];
#pragma unroll
      for (int mf = 0; mf < 4; ++mf)
        afr[mf] = *(const bf16x8*)&wA[(mf * 16 + n) * 576 + k];
      bf16x8 bfr[4];
#pragma unroll
      for (int nf = 0; nf < 4; ++nf) {
        const u16* p = lrow + (nf * 16 + n) * ICP + icl;
        bf16x4 lo = *(const bf16x4*)p;
        bf16x4 hi = *(const bf16x4*)(p + 4);
        bfr[nf] = __builtin_shufflevector(lo, hi, 0, 1, 2, 3, 4, 5, 6, 7);
      }
#pragma unroll
      for (int mf = 0; mf < 4; ++mf)
#pragma unroll
        for (int nf = 0; nf < 4; ++nf)
          acc[mf][nf] = __builtin_amdgcn_mfma_f32_16x16x32_bf16(
              afr[mf], bfr[nf], acc[mf][nf], 0, 0, 0);
    }
  }

  const int y = yb + wv;
#pragma unroll
  for (int mf = 0; mf < 4; ++mf) {
#pragma unroll
    for (int reg = 0; reg < 4; ++reg) {
      const int oc = mf * 16 + kg * 4 + reg;
      const float bv = bias[oc];
      const int rowbase = oc * NPIX + y * NX;
#pragma unroll
      for (int nf = 0; nf < 4; ++nf) {
        const int x = xb + nf * 16 + n;
        float v = acc[mf][nf][reg] + bv;
        if (ADDRES) v += res[rowbase + x];
        if (RELU) v = fmaxf(v, 0.f);
        if (OUT_BF)
          ((u16*)out_)[rowbase + x] = f2bf(v);
        else
          ((float*)out_)[rowbase + x] = v;
      }
    }
  }
}

// ---------------------------------------------------------------------------
// conv_out: 64 -> 1, fp32 in (residual stream), fp32 out, fp32 weights.
// ---------------------------------------------------------------------------
__global__ __launch_bounds__(256) void conv_out_kernel(
    const float* __restrict__ in, const float* __restrict__ w,
    const float* __restrict__ b, float* __restrict__ out) {
  const int p = blockIdx.x * 256 + threadIdx.x;
  const int gx = p & (NX - 1), gy = p >> 9;
  float a = b[0];
  for (int ic = 0; ic < 64; ++ic) {
    float v[9];
    load9(in + ic * NPIX, gx, gy, v);
    a = dot9(a, v, w + ic * 9);
  }
  out[p] = a;
}

// ---------------------------------------------------------------------------
extern "C" void kernel_launch(void* const* d_in, const int* in_sizes, int n_in,
                              void* d_out, int out_size, void* d_ws,
                              size_t ws_size, hipStream_t stream) {
  const float* x      = (const float*)d_in[0];
  const int*   indices= (const int*)d_in[1];
  const float* w1     = (const float*)d_in[2];
  const float* b1     = (const float*)d_in[3];
  const float* w2     = (const float*)d_in[4];
  const float* b2     = (const float*)d_in[5];
  const float* cin_w  = (const float*)d_in[6];
  const float* cin_b  = (const float*)d_in[7];
  const float* bw1    = (const float*)d_in[8];
  const float* bb1    = (const float*)d_in[9];
  const float* bw2    = (const float*)d_in[10];
  const float* bb2    = (const float*)d_in[11];
  const float* cout_w = (const float*)d_in[12];
  const float* cout_b = (const float*)d_in[13];

  float* ws   = (float*)d_ws;
  float* h1   = ws;                      // 360*736 f32
  float* h2   = h1 + VIEWS * NDET;       // 360*736 f32
  float* img  = h2 + VIEWS * NDET;       // NPIX f32
  float* yf   = img + NPIX;              // 64*NPIX f32 (residual stream)
  u16*  zb    = (u16*)(yf + 64 * NPIX);  // 64*NPIX bf16 (intra-block temp)
  u16*  wAll  = zb + 64 * NPIX;          // 22*64*576 bf16

  prep_weights_kernel<<<(22 * 36864 + 255) / 256, 256, 0, stream>>>(bw1, bw2,
                                                                    wAll);
  linear_relu_kernel<<<VIEWS, 256, 0, stream>>>(x, w1, b1, h1);
  linear_relu_kernel<<<VIEWS, 256, 0, stream>>>(h1, w2, b2, h2);
  backproj_kernel<<<NPIX / 256, 256, 0, stream>>>(h2, indices, img);
  conv_in_kernel<<<NPIX / 256, 256, 0, stream>>>(img, cin_w, cin_b, yf);

  for (int i = 0; i < 11; ++i) {
    // y (fp32) -> z (bf16), relu
    conv64_mfma<0, 1, 1, 0><<<1024, 256, 0, stream>>>(
        yf, wAll + i * 36864, bb1 + i * 64, nullptr, zb);
    // z (bf16) -> y (fp32), +res(y fp32), relu
    conv64_mfma<1, 0, 1, 1><<<1024, 256, 0, stream>>>(
        zb, wAll + (11 + i) * 36864, bb2 + i * 64, yf, yf);
  }
  conv_out_kernel<<<NPIX / 256, 256, 0, stream>>>(yf, cout_w, cout_b,
                                                  (float*)d_out);
}

// Round 5
// 2231.050 us; speedup vs baseline: 4.8128x; 1.1186x over previous
//
#include <hip/hip_runtime.h>

#define VIEWS 360
#define NDET 736
#define NX 512
#define NY 512
#define NPIX (NX * NY)
#define ICP 72  // LDS x-stride in u16: 144B = 36 dwords -> bank-uniform, 16B-aligned

typedef unsigned short u16;
typedef __attribute__((ext_vector_type(8))) short bf16x8;
typedef __attribute__((ext_vector_type(4))) float f32x4;

__device__ __forceinline__ u16 f2bf(float f) {
  unsigned u = __float_as_uint(f);
  return (u16)((u + 0x7fffu + ((u >> 16) & 1u)) >> 16);
}

// ---------------------------------------------------------------------------
// Linear layer: out[v,d] = relu(b[d] + sum_k in[v,k] * w[d,k])
// ---------------------------------------------------------------------------
__global__ __launch_bounds__(256) void linear_relu_kernel(
    const float* __restrict__ in, const float* __restrict__ w,
    const float* __restrict__ b, float* __restrict__ out) {
  __shared__ __align__(16) float xin[NDET];
  const int v = blockIdx.x;
  const float4* src4 = (const float4*)(in + v * NDET);
  float4* dst4 = (float4*)xin;
  for (int k = threadIdx.x; k < NDET / 4; k += 256) dst4[k] = src4[k];
  __syncthreads();

  for (int d = threadIdx.x; d < NDET; d += 256) {
    const float4* w4 = (const float4*)(w + d * NDET);
    float acc = 0.f;
#pragma unroll 8
    for (int k = 0; k < NDET / 4; ++k) {
      float4 xv = ((const float4*)xin)[k];
      float4 wv = w4[k];
      acc = fmaf(xv.x, wv.x, acc);
      acc = fmaf(xv.y, wv.y, acc);
      acc = fmaf(xv.z, wv.z, acc);
      acc = fmaf(xv.w, wv.w, acc);
    }
    out[v * NDET + d] = fmaxf(acc + b[d], 0.f);
  }
}

// ---------------------------------------------------------------------------
// Backprojection (fp32 in/out, writes flipped image, HW plane layout)
// ---------------------------------------------------------------------------
__global__ __launch_bounds__(256) void backproj_kernel(
    const float* __restrict__ sino, const int* __restrict__ idx,
    float* __restrict__ img) {
  const int p = blockIdx.x * 256 + threadIdx.x;
  const int4* ip4 = (const int4*)(idx + (size_t)p * VIEWS);
  float acc = 0.f;
#pragma unroll 5
  for (int a = 0; a < VIEWS / 4; ++a) {
    int4 v = ip4[a];
    acc += sino[v.x];
    acc += sino[v.y];
    acc += sino[v.z];
    acc += sino[v.w];
  }
  const int ix = p >> 9, iy = p & 511;
  const int q = (NX - 1 - ix) * NY + (NY - 1 - iy);
  img[q] = acc * 0.00872665f;  // END_ANGLE / (2*VIEWS)
}

// ---------------------------------------------------------------------------
// fp32 3x3 neighborhood load (zero pad), single plane
// ---------------------------------------------------------------------------
__device__ __forceinline__ void load9(const float* __restrict__ base, int gx,
                                      int gy, float v[9]) {
  const bool xm = gx > 0, xp = gx < NX - 1, ym = gy > 0, yp = gy < NY - 1;
  const float* c = base + gy * NX + gx;
  v[0] = (ym && xm) ? c[-NX - 1] : 0.f;
  v[1] = (ym)       ? c[-NX]     : 0.f;
  v[2] = (ym && xp) ? c[-NX + 1] : 0.f;
  v[3] = (xm)       ? c[-1]      : 0.f;
  v[4] =               c[0];
  v[5] = (xp)       ? c[1]       : 0.f;
  v[6] = (yp && xm) ? c[NX - 1]  : 0.f;
  v[7] = (yp)       ? c[NX]      : 0.f;
  v[8] = (yp && xp) ? c[NX + 1]  : 0.f;
}

__device__ __forceinline__ float dot9(float a, const float v[9],
                                      const float* __restrict__ w) {
  a = fmaf(v[0], w[0], a);
  a = fmaf(v[1], w[1], a);
  a = fmaf(v[2], w[2], a);
  a = fmaf(v[3], w[3], a);
  a = fmaf(v[4], w[4], a);
  a = fmaf(v[5], w[5], a);
  a = fmaf(v[6], w[6], a);
  a = fmaf(v[7], w[7], a);
  a = fmaf(v[8], w[8], a);
  return a;
}

// ---------------------------------------------------------------------------
// conv_in: 1 -> 64 channels, fp32 plane in -> fp32 NHWC out ([y][x][c]).
// ---------------------------------------------------------------------------
__global__ __launch_bounds__(256) void conv_in_kernel(
    const float* __restrict__ in, const float* __restrict__ w,
    const float* __restrict__ b, float* __restrict__ out) {
  const int p = blockIdx.x * 256 + threadIdx.x;
  const int gx = p & (NX - 1), gy = p >> 9;
  float v[9];
  load9(in, gx, gy, v);
  float* o = out + (size_t)p * 64;
#pragma unroll
  for (int oc = 0; oc < 64; ++oc) {
    float a = dot9(b[oc], v, w + oc * 9);
    o[oc] = fmaxf(a, 0.f);
  }
}

// ---------------------------------------------------------------------------
// Weight prep: fp32 w[oc][ic][3][3] -> bf16 wAll[layer][oc][k], k = tap*64+ic
// ---------------------------------------------------------------------------
__global__ __launch_bounds__(256) void prep_weights_kernel(
    const float* __restrict__ bw1, const float* __restrict__ bw2,
    u16* __restrict__ wAll) {
  const int g = blockIdx.x * 256 + threadIdx.x;
  if (g >= 22 * 36864) return;
  const int li = g / 36864, rm = g % 36864;
  const int oc = rm / 576, k = rm % 576;
  const int tap = k >> 6, ic = k & 63;
  const float* src = (li < 11) ? bw1 + li * 36864 : bw2 + (li - 11) * 36864;
  wAll[g] = f2bf(src[(oc * 64 + ic) * 9 + tap]);
}

// ---------------------------------------------------------------------------
// conv64 MFMA implicit GEMM, NHWC activations. M=64 oc, N=64x*4y, K=576.
// IN_BF: input NHWC bf16, else NHWC fp32 (cvt during staging).
// OUT_BF: output NHWC bf16, else fp32. res (fp32 NHWC) added when ADDRES.
// LDS tile: [r=6][xi=66][ICP=72] u16 (57 KB) -> 2 blocks/CU.
// B-frag = 16B-aligned ds_read_b128, bank-uniform. A-frag = 16B global (L1/L2).
// mfma_f32_16x16x32_bf16; C/D col=lane&15, row=(lane>>4)*4+reg (m89-verified).
// ---------------------------------------------------------------------------
template <int IN_BF, int OUT_BF, int RELU, int ADDRES>
__global__ __launch_bounds__(256, 2) void conv64_mfma(
    const void* __restrict__ in_, const u16* __restrict__ wA,
    const float* __restrict__ bias, const float* __restrict__ res,
    void* __restrict__ out_) {
  __shared__ u16 lds[6 * 66 * ICP];
  const int xb = (blockIdx.x & 7) * 64;
  const int yb = (int)(blockIdx.x >> 3) * 4;
  const int tid = threadIdx.x;

  // stage: 6 rows x 66 x-positions x 64 ch, 16B chunks (8 ch), no transpose.
#pragma unroll 1
  for (int it = 0; it < 13; ++it) {
    const int g = it * 256 + tid;
    if (g < 3168) {
      const int icq = g & 7;       // 8-ch chunk
      const int xr = g >> 3;       // r*66 + x66
      const int x66 = xr % 66;
      const int r = xr / 66;
      const int y = yb - 1 + r;
      const int x = xb - 1 + x66;
      uint4 d = {0u, 0u, 0u, 0u};
      if ((unsigned)y < 512u && (unsigned)x < 512u) {
        const size_t gi = ((size_t)((y << 9) + x)) * 64 + icq * 8;
        if (IN_BF) {
          d = *(const uint4*)&((const u16*)in_)[gi];
        } else {
          const float* s = &((const float*)in_)[gi];
          float4 f0 = *(const float4*)s;
          float4 f1 = *(const float4*)(s + 4);
          d.x = (unsigned)f2bf(f0.x) | ((unsigned)f2bf(f0.y) << 16);
          d.y = (unsigned)f2bf(f0.z) | ((unsigned)f2bf(f0.w) << 16);
          d.z = (unsigned)f2bf(f1.x) | ((unsigned)f2bf(f1.y) << 16);
          d.w = (unsigned)f2bf(f1.z) | ((unsigned)f2bf(f1.w) << 16);
        }
      }
      *(uint4*)&lds[xr * ICP + icq * 8] = d;
    }
  }
  __syncthreads();

  const int wv = tid >> 6;   // y-offset 0..3
  const int lane = tid & 63;
  const int n = lane & 15;
  const int kg = lane >> 4;

  f32x4 acc[4][4];
#pragma unroll
  for (int i = 0; i < 4; ++i)
#pragma unroll
    for (int j = 0; j < 4; ++j) acc[i][j] = (f32x4){0.f, 0.f, 0.f, 0.f};

#pragma unroll 1
  for (int tap = 0; tap < 9; ++tap) {
    const int r = wv + tap / 3;
    const int dxp1 = tap % 3;  // xi offset for output col 0
#pragma unroll
    for (int kb = 0; kb < 2; ++kb) {
      const int icl = kb * 32 + kg * 8;
      const int k = tap * 64 + icl;
      bf16x8 afr[4];
#pragma unroll
      for (int mf = 0; mf < 4; ++mf)
        afr[mf] = *(const bf16x8*)&wA[(mf * 16 + n) * 576 + k];
      bf16x8 bfr[4];
#pragma unroll
      for (int nf = 0; nf < 4; ++nf)
        bfr[nf] = *(const bf16x8*)&lds[(r * 66 + dxp1 + nf * 16 + n) * ICP + icl];
#pragma unroll
      for (int mf = 0; mf < 4; ++mf)
#pragma unroll
        for (int nf = 0; nf < 4; ++nf)
          acc[mf][nf] = __builtin_amdgcn_mfma_f32_16x16x32_bf16(
              afr[mf], bfr[nf], acc[mf][nf], 0, 0, 0);
    }
  }

  const int y = yb + wv;
#pragma unroll
  for (int mf = 0; mf < 4; ++mf) {
    const float4 bv = *(const float4*)&bias[mf * 16 + kg * 4];
#pragma unroll
    for (int nf = 0; nf < 4; ++nf) {
      const int x = xb + nf * 16 + n;
      const size_t base = ((size_t)((y << 9) + x)) * 64 + mf * 16 + kg * 4;
      float v0 = acc[mf][nf][0] + bv.x;
      float v1 = acc[mf][nf][1] + bv.y;
      float v2 = acc[mf][nf][2] + bv.z;
      float v3 = acc[mf][nf][3] + bv.w;
      if (ADDRES) {
        float4 rr = *(const float4*)&res[base];
        v0 += rr.x; v1 += rr.y; v2 += rr.z; v3 += rr.w;
      }
      if (RELU) {
        v0 = fmaxf(v0, 0.f); v1 = fmaxf(v1, 0.f);
        v2 = fmaxf(v2, 0.f); v3 = fmaxf(v3, 0.f);
      }
      if (OUT_BF) {
        uint2 pk;
        pk.x = (unsigned)f2bf(v0) | ((unsigned)f2bf(v1) << 16);
        pk.y = (unsigned)f2bf(v2) | ((unsigned)f2bf(v3) << 16);
        *(uint2*)&((u16*)out_)[base] = pk;
      } else {
        *(float4*)&((float*)out_)[base] = (float4){v0, v1, v2, v3};
      }
    }
  }
}

// ---------------------------------------------------------------------------
// conv_out: 64 -> 1, fp32 NHWC in, fp32 plane out.
// ---------------------------------------------------------------------------
__global__ __launch_bounds__(256) void conv_out_kernel(
    const float* __restrict__ in, const float* __restrict__ w,
    const float* __restrict__ b, float* __restrict__ out) {
  const int p = blockIdx.x * 256 + threadIdx.x;
  const int gx = p & (NX - 1), gy = p >> 9;
  float a = b[0];
#pragma unroll
  for (int ty = 0; ty < 3; ++ty) {
#pragma unroll
    for (int tx = 0; tx < 3; ++tx) {
      const int yy = gy + ty - 1, xx = gx + tx - 1;
      if ((unsigned)yy < 512u && (unsigned)xx < 512u) {
        const float* q = in + ((size_t)((yy << 9) + xx)) * 64;
        const int tap = ty * 3 + tx;
#pragma unroll 16
        for (int c = 0; c < 64; ++c) a = fmaf(q[c], w[c * 9 + tap], a);
      }
    }
  }
  out[p] = a;
}

// ---------------------------------------------------------------------------
extern "C" void kernel_launch(void* const* d_in, const int* in_sizes, int n_in,
                              void* d_out, int out_size, void* d_ws,
                              size_t ws_size, hipStream_t stream) {
  const float* x      = (const float*)d_in[0];
  const int*   indices= (const int*)d_in[1];
  const float* w1     = (const float*)d_in[2];
  const float* b1     = (const float*)d_in[3];
  const float* w2     = (const float*)d_in[4];
  const float* b2     = (const float*)d_in[5];
  const float* cin_w  = (const float*)d_in[6];
  const float* cin_b  = (const float*)d_in[7];
  const float* bw1    = (const float*)d_in[8];
  const float* bb1    = (const float*)d_in[9];
  const float* bw2    = (const float*)d_in[10];
  const float* bb2    = (const float*)d_in[11];
  const float* cout_w = (const float*)d_in[12];
  const float* cout_b = (const float*)d_in[13];

  float* ws   = (float*)d_ws;
  float* h1   = ws;                      // 360*736 f32
  float* h2   = h1 + VIEWS * NDET;       // 360*736 f32
  float* img  = h2 + VIEWS * NDET;       // NPIX f32 (plane)
  float* yf   = img + NPIX;              // 64*NPIX f32 NHWC (residual stream)
  u16*  zb    = (u16*)(yf + 64 * NPIX);  // 64*NPIX bf16 NHWC
  u16*  wAll  = zb + 64 * NPIX;          // 22*64*576 bf16

  prep_weights_kernel<<<(22 * 36864 + 255) / 256, 256, 0, stream>>>(bw1, bw2,
                                                                    wAll);
  linear_relu_kernel<<<VIEWS, 256, 0, stream>>>(x, w1, b1, h1);
  linear_relu_kernel<<<VIEWS, 256, 0, stream>>>(h1, w2, b2, h2);
  backproj_kernel<<<NPIX / 256, 256, 0, stream>>>(h2, indices, img);
  conv_in_kernel<<<NPIX / 256, 256, 0, stream>>>(img, cin_w, cin_b, yf);

  for (int i = 0; i < 11; ++i) {
    // y (fp32 NHWC) -> z (bf16 NHWC), relu
    conv64_mfma<0, 1, 1, 0><<<1024, 256, 0, stream>>>(
        yf, wAll + i * 36864, bb1 + i * 64, nullptr, zb);
    // z (bf16 NHWC) -> y (fp32 NHWC), +res(y), relu
    conv64_mfma<1, 0, 1, 1><<<1024, 256, 0, stream>>>(
        zb, wAll + (11 + i) * 36864, bb2 + i * 64, yf, yf);
  }
  conv_out_kernel<<<NPIX / 256, 256, 0, stream>>>(yf, cout_w, cout_b,
                                                  (float*)d_out);
}

// Round 6
// 2183.234 us; speedup vs baseline: 4.9182x; 1.0219x over previous
//
#include <hip/hip_runtime.h>

#define VIEWS 360
#define NDET 736
#define NX 512
#define NY 512
#define NPIX (NX * NY)

typedef unsigned short u16;
typedef __attribute__((ext_vector_type(8))) short bf16x8;
typedef __attribute__((ext_vector_type(4))) float f32x4;

__device__ __forceinline__ u16 f2bf(float f) {
  unsigned u = __float_as_uint(f);
  return (u16)((u + 0x7fffu + ((u >> 16) & 1u)) >> 16);
}

// ---------------------------------------------------------------------------
// Linear layer: out[v,d] = relu(b[d] + sum_k in[v,k] * w[d,k])
// ---------------------------------------------------------------------------
__global__ __launch_bounds__(256) void linear_relu_kernel(
    const float* __restrict__ in, const float* __restrict__ w,
    const float* __restrict__ b, float* __restrict__ out) {
  __shared__ __align__(16) float xin[NDET];
  const int v = blockIdx.x;
  const float4* src4 = (const float4*)(in + v * NDET);
  float4* dst4 = (float4*)xin;
  for (int k = threadIdx.x; k < NDET / 4; k += 256) dst4[k] = src4[k];
  __syncthreads();

  for (int d = threadIdx.x; d < NDET; d += 256) {
    const float4* w4 = (const float4*)(w + d * NDET);
    float acc = 0.f;
#pragma unroll 8
    for (int k = 0; k < NDET / 4; ++k) {
      float4 xv = ((const float4*)xin)[k];
      float4 wv = w4[k];
      acc = fmaf(xv.x, wv.x, acc);
      acc = fmaf(xv.y, wv.y, acc);
      acc = fmaf(xv.z, wv.z, acc);
      acc = fmaf(xv.w, wv.w, acc);
    }
    out[v * NDET + d] = fmaxf(acc + b[d], 0.f);
  }
}

// ---------------------------------------------------------------------------
// Backprojection, coalesced: 128 threads per pixel, lane j reads int4 chunk
// idx[p*360 + 4j] (consecutive lanes -> consecutive 16B). LDS tree-reduce.
// ---------------------------------------------------------------------------
__global__ __launch_bounds__(256) void backproj_kernel(
    const float* __restrict__ sino, const int* __restrict__ idx,
    float* __restrict__ img) {
  __shared__ float red[256];
  const int t = threadIdx.x;
  const int half = t >> 7, j = t & 127;
  const int p = blockIdx.x * 2 + half;
  float part = 0.f;
  if (j < 90) {
    int4 v = *(const int4*)&idx[(size_t)p * VIEWS + j * 4];
    part = sino[v.x] + sino[v.y] + sino[v.z] + sino[v.w];
  }
  red[t] = part;
  __syncthreads();
#pragma unroll
  for (int s = 64; s > 0; s >>= 1) {
    if ((t & 127) < s) red[t] += red[t + s];
    __syncthreads();
  }
  if (j == 0) {
    const int ix = p >> 9, iy = p & 511;
    img[(NX - 1 - ix) * NY + (NY - 1 - iy)] = red[t] * 0.00872665f;
  }
}

// ---------------------------------------------------------------------------
// fp32 3x3 neighborhood load (zero pad), single plane
// ---------------------------------------------------------------------------
__device__ __forceinline__ void load9(const float* __restrict__ base, int gx,
                                      int gy, float v[9]) {
  const bool xm = gx > 0, xp = gx < NX - 1, ym = gy > 0, yp = gy < NY - 1;
  const float* c = base + gy * NX + gx;
  v[0] = (ym && xm) ? c[-NX - 1] : 0.f;
  v[1] = (ym)       ? c[-NX]     : 0.f;
  v[2] = (ym && xp) ? c[-NX + 1] : 0.f;
  v[3] = (xm)       ? c[-1]      : 0.f;
  v[4] =               c[0];
  v[5] = (xp)       ? c[1]       : 0.f;
  v[6] = (yp && xm) ? c[NX - 1]  : 0.f;
  v[7] = (yp)       ? c[NX]      : 0.f;
  v[8] = (yp && xp) ? c[NX + 1]  : 0.f;
}

__device__ __forceinline__ float dot9(float a, const float v[9],
                                      const float* __restrict__ w) {
  a = fmaf(v[0], w[0], a);
  a = fmaf(v[1], w[1], a);
  a = fmaf(v[2], w[2], a);
  a = fmaf(v[3], w[3], a);
  a = fmaf(v[4], w[4], a);
  a = fmaf(v[5], w[5], a);
  a = fmaf(v[6], w[6], a);
  a = fmaf(v[7], w[7], a);
  a = fmaf(v[8], w[8], a);
  return a;
}

// ---------------------------------------------------------------------------
// conv_in: 1 -> 64 channels, fp32 plane in -> fp32 NHWC out, float4 stores.
// ---------------------------------------------------------------------------
__global__ __launch_bounds__(256) void conv_in_kernel(
    const float* __restrict__ in, const float* __restrict__ w,
    const float* __restrict__ b, float* __restrict__ out) {
  const int p = blockIdx.x * 256 + threadIdx.x;
  const int gx = p & (NX - 1), gy = p >> 9;
  float v[9];
  load9(in, gx, gy, v);
  float4* o = (float4*)(out + (size_t)p * 64);
#pragma unroll
  for (int oq = 0; oq < 16; ++oq) {
    float4 r;
    r.x = fmaxf(dot9(b[oq * 4 + 0], v, w + (oq * 4 + 0) * 9), 0.f);
    r.y = fmaxf(dot9(b[oq * 4 + 1], v, w + (oq * 4 + 1) * 9), 0.f);
    r.z = fmaxf(dot9(b[oq * 4 + 2], v, w + (oq * 4 + 2) * 9), 0.f);
    r.w = fmaxf(dot9(b[oq * 4 + 3], v, w + (oq * 4 + 3) * 9), 0.f);
    o[oq] = r;
  }
}

// ---------------------------------------------------------------------------
// Weight prep -> per-step wave-contiguous layout:
// wR[li][s=tap*2+kb][lane=kg*16+n][mf][j] = W[li][oc=mf*16+n][ic=kb*32+kg*8+j][tap]
// A wave's A-load per step = one contiguous 4 KB burst.
// ---------------------------------------------------------------------------
__global__ __launch_bounds__(256) void prep_weights_kernel(
    const float* __restrict__ bw1, const float* __restrict__ bw2,
    u16* __restrict__ wR) {
  const int g = blockIdx.x * 256 + threadIdx.x;
  if (g >= 22 * 36864) return;
  const int li = g / 36864, r1 = g % 36864;
  const int s = r1 / 2048, r2 = r1 % 2048;
  const int lane = r2 / 32, r3 = r2 % 32;
  const int mf = r3 / 8, j = r3 % 8;
  const int tap = s >> 1, kb = s & 1;
  const int kg = lane >> 4, n = lane & 15;
  const int oc = mf * 16 + n;
  const int ic = kb * 32 + kg * 8 + j;
  const float* src = (li < 11) ? bw1 + li * 36864 : bw2 + (li - 11) * 36864;
  wR[g] = f2bf(src[(oc * 64 + ic) * 9 + tap]);
}

// ---------------------------------------------------------------------------
// conv64 MFMA implicit GEMM, NHWC. M=64 oc, N=64x*4y, K=576.
// LDS tile [r=6][xi=66][8 chunks of 8ch], XOR-swizzled (slot = q ^ (xi&7))
// -> 50.7 KB, conflict-free, 3 blocks/CU. A-loads software-pipelined.
// mfma_f32_16x16x32_bf16; C/D col=lane&15, row=(lane>>4)*4+reg (m89-verified).
// ---------------------------------------------------------------------------
template <int IN_BF, int OUT_BF, int RELU, int ADDRES>
__global__ __launch_bounds__(256, 3) void conv64_mfma(
    const void* __restrict__ in_, const u16* __restrict__ wA,
    const float* __restrict__ bias, const float* __restrict__ res,
    void* __restrict__ out_) {
  __shared__ u16 lds[6 * 66 * 64];
  const int xb = (blockIdx.x & 7) * 64;
  const int yb = (int)(blockIdx.x >> 3) * 4;
  const int tid = threadIdx.x;

  // stage: 6 rows x 66 x x 64 ch as 16B chunks; slot = icq ^ (x66 & 7)
#pragma unroll 1
  for (int it = 0; it < 13; ++it) {
    const int g = it * 256 + tid;
    if (g < 3168) {
      const int icq = g & 7;
      const int xr = g >> 3;
      const int x66 = xr % 66;
      const int r = xr / 66;
      const int y = yb - 1 + r;
      const int x = xb - 1 + x66;
      uint4 d = {0u, 0u, 0u, 0u};
      if ((unsigned)y < 512u && (unsigned)x < 512u) {
        const size_t gi = ((size_t)((y << 9) + x)) * 64 + icq * 8;
        if (IN_BF) {
          d = *(const uint4*)&((const u16*)in_)[gi];
        } else {
          const float* s = &((const float*)in_)[gi];
          float4 f0 = *(const float4*)s;
          float4 f1 = *(const float4*)(s + 4);
          d.x = (unsigned)f2bf(f0.x) | ((unsigned)f2bf(f0.y) << 16);
          d.y = (unsigned)f2bf(f0.z) | ((unsigned)f2bf(f0.w) << 16);
          d.z = (unsigned)f2bf(f1.x) | ((unsigned)f2bf(f1.y) << 16);
          d.w = (unsigned)f2bf(f1.z) | ((unsigned)f2bf(f1.w) << 16);
        }
      }
      const int slot = icq ^ (x66 & 7);
      *(uint4*)&lds[(xr * 8 + slot) * 8] = d;
    }
  }
  __syncthreads();

  const int wv = tid >> 6;   // y-offset 0..3
  const int lane = tid & 63;
  const int n = lane & 15;
  const int kg = lane >> 4;

  f32x4 acc[4][4];
#pragma unroll
  for (int i = 0; i < 4; ++i)
#pragma unroll
    for (int j = 0; j < 4; ++j) acc[i][j] = (f32x4){0.f, 0.f, 0.f, 0.f};

  // A prefetch pipeline over 18 steps (s = tap*2 + kb)
  bf16x8 acur[4];
#pragma unroll
  for (int mf = 0; mf < 4; ++mf)
    acur[mf] = *(const bf16x8*)&wA[(size_t)lane * 32 + mf * 8];

#pragma unroll 1
  for (int s = 0; s < 18; ++s) {
    bf16x8 anxt[4];
    const int sn = (s < 17) ? s + 1 : s;
#pragma unroll
    for (int mf = 0; mf < 4; ++mf)
      anxt[mf] = *(const bf16x8*)&wA[((size_t)sn * 64 + lane) * 32 + mf * 8];

    const int tap = s >> 1, kb = s & 1;
    const int r = wv + tap / 3;
    const int dxp1 = tap % 3;
    const int q = kb * 4 + kg;  // 8-ch chunk index

    bf16x8 bfr[4];
#pragma unroll
    for (int nf = 0; nf < 4; ++nf) {
      const int xi = dxp1 + nf * 16 + n;
      const int slot = q ^ (xi & 7);
      bfr[nf] = *(const bf16x8*)&lds[((r * 66 + xi) * 8 + slot) * 8];
    }
#pragma unroll
    for (int mf = 0; mf < 4; ++mf)
#pragma unroll
      for (int nf = 0; nf < 4; ++nf)
        acc[mf][nf] = __builtin_amdgcn_mfma_f32_16x16x32_bf16(
            acur[mf], bfr[nf], acc[mf][nf], 0, 0, 0);
#pragma unroll
    for (int mf = 0; mf < 4; ++mf) acur[mf] = anxt[mf];
  }

  const int y = yb + wv;
#pragma unroll
  for (int mf = 0; mf < 4; ++mf) {
    const float4 bv = *(const float4*)&bias[mf * 16 + kg * 4];
#pragma unroll
    for (int nf = 0; nf < 4; ++nf) {
      const int x = xb + nf * 16 + n;
      const size_t base = ((size_t)((y << 9) + x)) * 64 + mf * 16 + kg * 4;
      float v0 = acc[mf][nf][0] + bv.x;
      float v1 = acc[mf][nf][1] + bv.y;
      float v2 = acc[mf][nf][2] + bv.z;
      float v3 = acc[mf][nf][3] + bv.w;
      if (ADDRES) {
        float4 rr = *(const float4*)&res[base];
        v0 += rr.x; v1 += rr.y; v2 += rr.z; v3 += rr.w;
      }
      if (RELU) {
        v0 = fmaxf(v0, 0.f); v1 = fmaxf(v1, 0.f);
        v2 = fmaxf(v2, 0.f); v3 = fmaxf(v3, 0.f);
      }
      if (OUT_BF) {
        uint2 pk;
        pk.x = (unsigned)f2bf(v0) | ((unsigned)f2bf(v1) << 16);
        pk.y = (unsigned)f2bf(v2) | ((unsigned)f2bf(v3) << 16);
        *(uint2*)&((u16*)out_)[base] = pk;
      } else {
        *(float4*)&((float*)out_)[base] = (float4){v0, v1, v2, v3};
      }
    }
  }
}

// ---------------------------------------------------------------------------
// conv_out: 64 -> 1, fp32 NHWC in (float4 loads), fp32 plane out.
// ---------------------------------------------------------------------------
__global__ __launch_bounds__(256) void conv_out_kernel(
    const float* __restrict__ in, const float* __restrict__ w,
    const float* __restrict__ b, float* __restrict__ out) {
  const int p = blockIdx.x * 256 + threadIdx.x;
  const int gx = p & (NX - 1), gy = p >> 9;
  float a = b[0];
#pragma unroll
  for (int ty = 0; ty < 3; ++ty) {
#pragma unroll
    for (int tx = 0; tx < 3; ++tx) {
      const int yy = gy + ty - 1, xx = gx + tx - 1;
      if ((unsigned)yy < 512u && (unsigned)xx < 512u) {
        const float4* q = (const float4*)(in + ((size_t)((yy << 9) + xx)) * 64);
        const int tap = ty * 3 + tx;
#pragma unroll
        for (int i = 0; i < 16; ++i) {
          float4 d = q[i];
          a = fmaf(d.x, w[(i * 4 + 0) * 9 + tap], a);
          a = fmaf(d.y, w[(i * 4 + 1) * 9 + tap], a);
          a = fmaf(d.z, w[(i * 4 + 2) * 9 + tap], a);
          a = fmaf(d.w, w[(i * 4 + 3) * 9 + tap], a);
        }
      }
    }
  }
  out[p] = a;
}

// ---------------------------------------------------------------------------
extern "C" void kernel_launch(void* const* d_in, const int* in_sizes, int n_in,
                              void* d_out, int out_size, void* d_ws,
                              size_t ws_size, hipStream_t stream) {
  const float* x      = (const float*)d_in[0];
  const int*   indices= (const int*)d_in[1];
  const float* w1     = (const float*)d_in[2];
  const float* b1     = (const float*)d_in[3];
  const float* w2     = (const float*)d_in[4];
  const float* b2     = (const float*)d_in[5];
  const float* cin_w  = (const float*)d_in[6];
  const float* cin_b  = (const float*)d_in[7];
  const float* bw1    = (const float*)d_in[8];
  const float* bb1    = (const float*)d_in[9];
  const float* bw2    = (const float*)d_in[10];
  const float* bb2    = (const float*)d_in[11];
  const float* cout_w = (const float*)d_in[12];
  const float* cout_b = (const float*)d_in[13];

  float* ws   = (float*)d_ws;
  float* h1   = ws;                      // 360*736 f32
  float* h2   = h1 + VIEWS * NDET;       // 360*736 f32
  float* img  = h2 + VIEWS * NDET;       // NPIX f32 (plane)
  float* yf   = img + NPIX;              // 64*NPIX f32 NHWC (residual stream)
  u16*  zb    = (u16*)(yf + 64 * NPIX);  // 64*NPIX bf16 NHWC
  u16*  wAll  = zb + 64 * NPIX;          // 22*64*576 bf16 (step layout)

  prep_weights_kernel<<<(22 * 36864 + 255) / 256, 256, 0, stream>>>(bw1, bw2,
                                                                    wAll);
  linear_relu_kernel<<<VIEWS, 256, 0, stream>>>(x, w1, b1, h1);
  linear_relu_kernel<<<VIEWS, 256, 0, stream>>>(h1, w2, b2, h2);
  backproj_kernel<<<NPIX / 2, 256, 0, stream>>>(h2, indices, img);
  conv_in_kernel<<<NPIX / 256, 256, 0, stream>>>(img, cin_w, cin_b, yf);

  for (int i = 0; i < 11; ++i) {
    // y (fp32 NHWC) -> z (bf16 NHWC), relu
    conv64_mfma<0, 1, 1, 0><<<1024, 256, 0, stream>>>(
        yf, wAll + i * 36864, bb1 + i * 64, nullptr, zb);
    // z (bf16 NHWC) -> y (fp32 NHWC), +res(y), relu
    conv64_mfma<1, 0, 1, 1><<<1024, 256, 0, stream>>>(
        zb, wAll + (11 + i) * 36864, bb2 + i * 64, yf, yf);
  }
  conv_out_kernel<<<NPIX / 256, 256, 0, stream>>>(yf, cout_w, cout_b,
                                                  (float*)d_out);
}

// Round 7
// 1953.623 us; speedup vs baseline: 5.4962x; 1.1175x over previous
//
#include <hip/hip_runtime.h>

#define VIEWS 360
#define NDET 736
#define NX 512
#define NY 512
#define NPIX (NX * NY)

typedef unsigned short u16;
typedef __attribute__((ext_vector_type(8))) short bf16x8;
typedef __attribute__((ext_vector_type(4))) float f32x4;

__device__ __forceinline__ u16 f2bf(float f) {
  unsigned u = __float_as_uint(f);
  return (u16)((u + 0x7fffu + ((u >> 16) & 1u)) >> 16);
}

// ---------------------------------------------------------------------------
// Linear layer: out[v,d] = relu(b[d] + sum_k in[v,k] * w[d,k])
// ---------------------------------------------------------------------------
__global__ __launch_bounds__(256) void linear_relu_kernel(
    const float* __restrict__ in, const float* __restrict__ w,
    const float* __restrict__ b, float* __restrict__ out) {
  __shared__ __align__(16) float xin[NDET];
  const int v = blockIdx.x;
  const float4* src4 = (const float4*)(in + v * NDET);
  float4* dst4 = (float4*)xin;
  for (int k = threadIdx.x; k < NDET / 4; k += 256) dst4[k] = src4[k];
  __syncthreads();

  for (int d = threadIdx.x; d < NDET; d += 256) {
    const float4* w4 = (const float4*)(w + d * NDET);
    float acc = 0.f;
#pragma unroll 8
    for (int k = 0; k < NDET / 4; ++k) {
      float4 xv = ((const float4*)xin)[k];
      float4 wv = w4[k];
      acc = fmaf(xv.x, wv.x, acc);
      acc = fmaf(xv.y, wv.y, acc);
      acc = fmaf(xv.z, wv.z, acc);
      acc = fmaf(xv.w, wv.w, acc);
    }
    out[v * NDET + d] = fmaxf(acc + b[d], 0.f);
  }
}

// ---------------------------------------------------------------------------
// Backprojection v3: thread-owns-pixel (wave gathers = same view, consecutive
// pixels -> few cache lines, L1-hot sino) + idx reads coalesced via LDS
// staging of 72-view chunks. Row pad 77 dwords (77 mod 32 = 13, coprime) ->
// conflict-free LDS reads. 78.8 KB LDS -> 2 blocks/CU.
// ---------------------------------------------------------------------------
__global__ __launch_bounds__(256) void backproj_kernel(
    const float* __restrict__ sino, const int* __restrict__ idx,
    float* __restrict__ img) {
  __shared__ int lidx[256 * 77];
  const int t = threadIdx.x;
  const int p_base = blockIdx.x * 256;

  float a0 = 0.f, a1 = 0.f, a2 = 0.f, a3 = 0.f;

#pragma unroll 1
  for (int c = 0; c < 5; ++c) {
    if (c) __syncthreads();
    // stage: 256 rows x 72 views, int4-coalesced from global
#pragma unroll
    for (int k = 0; k < 18; ++k) {
      const int f = k * 256 + t;
      const int row = f / 18, col4 = f % 18;
      int4 v = *(const int4*)&idx[(size_t)(p_base + row) * VIEWS + c * 72 +
                                  col4 * 4];
      int* dst = &lidx[row * 77 + col4 * 4];
      dst[0] = v.x; dst[1] = v.y; dst[2] = v.z; dst[3] = v.w;
    }
    __syncthreads();
    const int* myrow = &lidx[t * 77];
#pragma unroll
    for (int j = 0; j < 72; j += 4) {
      a0 += sino[myrow[j + 0]];
      a1 += sino[myrow[j + 1]];
      a2 += sino[myrow[j + 2]];
      a3 += sino[myrow[j + 3]];
    }
  }

  const int p = p_base + t;
  const int ix = p >> 9, iy = p & 511;
  img[(NX - 1 - ix) * NY + (NY - 1 - iy)] =
      ((a0 + a1) + (a2 + a3)) * 0.00872665f;  // END_ANGLE / (2*VIEWS)
}

// ---------------------------------------------------------------------------
// fp32 3x3 neighborhood load (zero pad), single plane
// ---------------------------------------------------------------------------
__device__ __forceinline__ void load9(const float* __restrict__ base, int gx,
                                      int gy, float v[9]) {
  const bool xm = gx > 0, xp = gx < NX - 1, ym = gy > 0, yp = gy < NY - 1;
  const float* c = base + gy * NX + gx;
  v[0] = (ym && xm) ? c[-NX - 1] : 0.f;
  v[1] = (ym)       ? c[-NX]     : 0.f;
  v[2] = (ym && xp) ? c[-NX + 1] : 0.f;
  v[3] = (xm)       ? c[-1]      : 0.f;
  v[4] =               c[0];
  v[5] = (xp)       ? c[1]       : 0.f;
  v[6] = (yp && xm) ? c[NX - 1]  : 0.f;
  v[7] = (yp)       ? c[NX]      : 0.f;
  v[8] = (yp && xp) ? c[NX + 1]  : 0.f;
}

__device__ __forceinline__ float dot9(float a, const float v[9],
                                      const float* __restrict__ w) {
  a = fmaf(v[0], w[0], a);
  a = fmaf(v[1], w[1], a);
  a = fmaf(v[2], w[2], a);
  a = fmaf(v[3], w[3], a);
  a = fmaf(v[4], w[4], a);
  a = fmaf(v[5], w[5], a);
  a = fmaf(v[6], w[6], a);
  a = fmaf(v[7], w[7], a);
  a = fmaf(v[8], w[8], a);
  return a;
}

// ---------------------------------------------------------------------------
// conv_in: 1 -> 64 channels, fp32 plane in -> fp32 NHWC out, float4 stores.
// ---------------------------------------------------------------------------
__global__ __launch_bounds__(256) void conv_in_kernel(
    const float* __restrict__ in, const float* __restrict__ w,
    const float* __restrict__ b, float* __restrict__ out) {
  const int p = blockIdx.x * 256 + threadIdx.x;
  const int gx = p & (NX - 1), gy = p >> 9;
  float v[9];
  load9(in, gx, gy, v);
  float4* o = (float4*)(out + (size_t)p * 64);
#pragma unroll
  for (int oq = 0; oq < 16; ++oq) {
    float4 r;
    r.x = fmaxf(dot9(b[oq * 4 + 0], v, w + (oq * 4 + 0) * 9), 0.f);
    r.y = fmaxf(dot9(b[oq * 4 + 1], v, w + (oq * 4 + 1) * 9), 0.f);
    r.z = fmaxf(dot9(b[oq * 4 + 2], v, w + (oq * 4 + 2) * 9), 0.f);
    r.w = fmaxf(dot9(b[oq * 4 + 3], v, w + (oq * 4 + 3) * 9), 0.f);
    o[oq] = r;
  }
}

// ---------------------------------------------------------------------------
// Weight prep -> per-step wave-contiguous layout:
// wR[li][s=tap*2+kb][lane=kg*16+n][mf][j] = W[li][oc=mf*16+n][ic=kb*32+kg*8+j][tap]
// ---------------------------------------------------------------------------
__global__ __launch_bounds__(256) void prep_weights_kernel(
    const float* __restrict__ bw1, const float* __restrict__ bw2,
    u16* __restrict__ wR) {
  const int g = blockIdx.x * 256 + threadIdx.x;
  if (g >= 22 * 36864) return;
  const int li = g / 36864, r1 = g % 36864;
  const int s = r1 / 2048, r2 = r1 % 2048;
  const int lane = r2 / 32, r3 = r2 % 32;
  const int mf = r3 / 8, j = r3 % 8;
  const int tap = s >> 1, kb = s & 1;
  const int kg = lane >> 4, n = lane & 15;
  const int oc = mf * 16 + n;
  const int ic = kb * 32 + kg * 8 + j;
  const float* src = (li < 11) ? bw1 + li * 36864 : bw2 + (li - 11) * 36864;
  wR[g] = f2bf(src[(oc * 64 + ic) * 9 + tap]);
}

// ---------------------------------------------------------------------------
// conv64 MFMA implicit GEMM, NHWC. M=64 oc, N=64x*4y, K=576.
// LDS tile [r=6][xi=66][8 chunks of 8ch], XOR-swizzled (slot = q ^ (xi&7))
// -> 50.7 KB, 3 blocks/CU. A-loads software-pipelined.
// mfma_f32_16x16x32_bf16; C/D col=lane&15, row=(lane>>4)*4+reg (m89-verified).
// ---------------------------------------------------------------------------
template <int IN_BF, int OUT_BF, int RELU, int ADDRES>
__global__ __launch_bounds__(256, 3) void conv64_mfma(
    const void* __restrict__ in_, const u16* __restrict__ wA,
    const float* __restrict__ bias, const float* __restrict__ res,
    void* __restrict__ out_) {
  __shared__ u16 lds[6 * 66 * 64];
  const int xb = (blockIdx.x & 7) * 64;
  const int yb = (int)(blockIdx.x >> 3) * 4;
  const int tid = threadIdx.x;

#pragma unroll 1
  for (int it = 0; it < 13; ++it) {
    const int g = it * 256 + tid;
    if (g < 3168) {
      const int icq = g & 7;
      const int xr = g >> 3;
      const int x66 = xr % 66;
      const int r = xr / 66;
      const int y = yb - 1 + r;
      const int x = xb - 1 + x66;
      uint4 d = {0u, 0u, 0u, 0u};
      if ((unsigned)y < 512u && (unsigned)x < 512u) {
        const size_t gi = ((size_t)((y << 9) + x)) * 64 + icq * 8;
        if (IN_BF) {
          d = *(const uint4*)&((const u16*)in_)[gi];
        } else {
          const float* s = &((const float*)in_)[gi];
          float4 f0 = *(const float4*)s;
          float4 f1 = *(const float4*)(s + 4);
          d.x = (unsigned)f2bf(f0.x) | ((unsigned)f2bf(f0.y) << 16);
          d.y = (unsigned)f2bf(f0.z) | ((unsigned)f2bf(f0.w) << 16);
          d.z = (unsigned)f2bf(f1.x) | ((unsigned)f2bf(f1.y) << 16);
          d.w = (unsigned)f2bf(f1.z) | ((unsigned)f2bf(f1.w) << 16);
        }
      }
      const int slot = icq ^ (x66 & 7);
      *(uint4*)&lds[(xr * 8 + slot) * 8] = d;
    }
  }
  __syncthreads();

  const int wv = tid >> 6;
  const int lane = tid & 63;
  const int n = lane & 15;
  const int kg = lane >> 4;

  f32x4 acc[4][4];
#pragma unroll
  for (int i = 0; i < 4; ++i)
#pragma unroll
    for (int j = 0; j < 4; ++j) acc[i][j] = (f32x4){0.f, 0.f, 0.f, 0.f};

  bf16x8 acur[4];
#pragma unroll
  for (int mf = 0; mf < 4; ++mf)
    acur[mf] = *(const bf16x8*)&wA[(size_t)lane * 32 + mf * 8];

#pragma unroll 1
  for (int s = 0; s < 18; ++s) {
    bf16x8 anxt[4];
    const int sn = (s < 17) ? s + 1 : s;
#pragma unroll
    for (int mf = 0; mf < 4; ++mf)
      anxt[mf] = *(const bf16x8*)&wA[((size_t)sn * 64 + lane) * 32 + mf * 8];

    const int tap = s >> 1, kb = s & 1;
    const int r = wv + tap / 3;
    const int dxp1 = tap % 3;
    const int q = kb * 4 + kg;

    bf16x8 bfr[4];
#pragma unroll
    for (int nf = 0; nf < 4; ++nf) {
      const int xi = dxp1 + nf * 16 + n;
      const int slot = q ^ (xi & 7);
      bfr[nf] = *(const bf16x8*)&lds[((r * 66 + xi) * 8 + slot) * 8];
    }
#pragma unroll
    for (int mf = 0; mf < 4; ++mf)
#pragma unroll
      for (int nf = 0; nf < 4; ++nf)
        acc[mf][nf] = __builtin_amdgcn_mfma_f32_16x16x32_bf16(
            acur[mf], bfr[nf], acc[mf][nf], 0, 0, 0);
#pragma unroll
    for (int mf = 0; mf < 4; ++mf) acur[mf] = anxt[mf];
  }

  const int y = yb + wv;
#pragma unroll
  for (int mf = 0; mf < 4; ++mf) {
    const float4 bv = *(const float4*)&bias[mf * 16 + kg * 4];
#pragma unroll
    for (int nf = 0; nf < 4; ++nf) {
      const int x = xb + nf * 16 + n;
      const size_t base = ((size_t)((y << 9) + x)) * 64 + mf * 16 + kg * 4;
      float v0 = acc[mf][nf][0] + bv.x;
      float v1 = acc[mf][nf][1] + bv.y;
      float v2 = acc[mf][nf][2] + bv.z;
      float v3 = acc[mf][nf][3] + bv.w;
      if (ADDRES) {
        float4 rr = *(const float4*)&res[base];
        v0 += rr.x; v1 += rr.y; v2 += rr.z; v3 += rr.w;
      }
      if (RELU) {
        v0 = fmaxf(v0, 0.f); v1 = fmaxf(v1, 0.f);
        v2 = fmaxf(v2, 0.f); v3 = fmaxf(v3, 0.f);
      }
      if (OUT_BF) {
        uint2 pk;
        pk.x = (unsigned)f2bf(v0) | ((unsigned)f2bf(v1) << 16);
        pk.y = (unsigned)f2bf(v2) | ((unsigned)f2bf(v3) << 16);
        *(uint2*)&((u16*)out_)[base] = pk;
      } else {
        *(float4*)&((float*)out_)[base] = (float4){v0, v1, v2, v3};
      }
    }
  }
}

// ---------------------------------------------------------------------------
// conv_out: 64 -> 1, fp32 NHWC in (float4 loads), fp32 plane out.
// ---------------------------------------------------------------------------
__global__ __launch_bounds__(256) void conv_out_kernel(
    const float* __restrict__ in, const float* __restrict__ w,
    const float* __restrict__ b, float* __restrict__ out) {
  const int p = blockIdx.x * 256 + threadIdx.x;
  const int gx = p & (NX - 1), gy = p >> 9;
  float a = b[0];
#pragma unroll
  for (int ty = 0; ty < 3; ++ty) {
#pragma unroll
    for (int tx = 0; tx < 3; ++tx) {
      const int yy = gy + ty - 1, xx = gx + tx - 1;
      if ((unsigned)yy < 512u && (unsigned)xx < 512u) {
        const float4* q = (const float4*)(in + ((size_t)((yy << 9) + xx)) * 64);
        const int tap = ty * 3 + tx;
#pragma unroll
        for (int i = 0; i < 16; ++i) {
          float4 d = q[i];
          a = fmaf(d.x, w[(i * 4 + 0) * 9 + tap], a);
          a = fmaf(d.y, w[(i * 4 + 1) * 9 + tap], a);
          a = fmaf(d.z, w[(i * 4 + 2) * 9 + tap], a);
          a = fmaf(d.w, w[(i * 4 + 3) * 9 + tap], a);
        }
      }
    }
  }
  out[p] = a;
}

// ---------------------------------------------------------------------------
extern "C" void kernel_launch(void* const* d_in, const int* in_sizes, int n_in,
                              void* d_out, int out_size, void* d_ws,
                              size_t ws_size, hipStream_t stream) {
  const float* x      = (const float*)d_in[0];
  const int*   indices= (const int*)d_in[1];
  const float* w1     = (const float*)d_in[2];
  const float* b1     = (const float*)d_in[3];
  const float* w2     = (const float*)d_in[4];
  const float* b2     = (const float*)d_in[5];
  const float* cin_w  = (const float*)d_in[6];
  const float* cin_b  = (const float*)d_in[7];
  const float* bw1    = (const float*)d_in[8];
  const float* bb1    = (const float*)d_in[9];
  const float* bw2    = (const float*)d_in[10];
  const float* bb2    = (const float*)d_in[11];
  const float* cout_w = (const float*)d_in[12];
  const float* cout_b = (const float*)d_in[13];

  float* ws   = (float*)d_ws;
  float* h1   = ws;                      // 360*736 f32
  float* h2   = h1 + VIEWS * NDET;       // 360*736 f32
  float* img  = h2 + VIEWS * NDET;       // NPIX f32 (plane)
  float* yf   = img + NPIX;              // 64*NPIX f32 NHWC (residual stream)
  u16*  zb    = (u16*)(yf + 64 * NPIX);  // 64*NPIX bf16 NHWC
  u16*  wAll  = zb + 64 * NPIX;          // 22*64*576 bf16 (step layout)

  prep_weights_kernel<<<(22 * 36864 + 255) / 256, 256, 0, stream>>>(bw1, bw2,
                                                                    wAll);
  linear_relu_kernel<<<VIEWS, 256, 0, stream>>>(x, w1, b1, h1);
  linear_relu_kernel<<<VIEWS, 256, 0, stream>>>(h1, w2, b2, h2);
  backproj_kernel<<<NPIX / 256, 256, 0, stream>>>(h2, indices, img);
  conv_in_kernel<<<NPIX / 256, 256, 0, stream>>>(img, cin_w, cin_b, yf);

  for (int i = 0; i < 11; ++i) {
    conv64_mfma<0, 1, 1, 0><<<1024, 256, 0, stream>>>(
        yf, wAll + i * 36864, bb1 + i * 64, nullptr, zb);
    conv64_mfma<1, 0, 1, 1><<<1024, 256, 0, stream>>>(
        zb, wAll + (11 + i) * 36864, bb2 + i * 64, yf, yf);
  }
  conv_out_kernel<<<NPIX / 256, 256, 0, stream>>>(yf, cout_w, cout_b,
                                                  (float*)d_out);
}